// Round 13
// baseline (71.583 us; speedup 1.0000x reference)
//
#include <hip/hip_runtime.h>

#define NQ     50000
#define MS     50000
#define NH     32
#define NK     15
#define CIN    64
#define COUT   128
#define QT     32
#define INV_EXT (1.0f/0.06f)

typedef unsigned int   uint32;
typedef unsigned short u16;
typedef _Float16 f16;
typedef _Float16 f16x8 __attribute__((ext_vector_type(8)));
typedef float    f32x4 __attribute__((ext_vector_type(4)));

#define WB_BYTES  (8*32*64*8*2)   // 262144: W packed for K'=c*16+k enumeration (K=1024)
#define XPH_BYTES (MS*CIN*2)      // 6,400,000: x fp16, channel-permuted

#if __has_builtin(__builtin_amdgcn_sqrtf)
#define SQRTF __builtin_amdgcn_sqrtf
#else
#define SQRTF sqrtf
#endif

// dst = (A.lo16, B.lo16) / (A.hi16, B.hi16)
__device__ __forceinline__ uint32 permlo(uint32 A, uint32 B) {
#if __has_builtin(__builtin_amdgcn_perm)
    return __builtin_amdgcn_perm(A, B, 0x01000504u);
#else
    return (A & 0xffffu) | (B << 16);
#endif
}
__device__ __forceinline__ uint32 permhi(uint32 A, uint32 B) {
#if __has_builtin(__builtin_amdgcn_perm)
    return __builtin_amdgcn_perm(A, B, 0x03020706u);
#else
    return (A >> 16) | (B & 0xffff0000u);
#endif
}

__device__ __forceinline__ u16 f16bits(float f) {
    return __builtin_bit_cast(u16, (f16)f);
}

// packed f32x2 -> f16x2 bits (one v_cvt_pkrtz_f16_f32)
__device__ __forceinline__ uint32 pk2(float a, float b) {
#if __has_builtin(__builtin_amdgcn_cvt_pkrtz)
    return __builtin_bit_cast(uint32, __builtin_amdgcn_cvt_pkrtz(a, b));
#else
    return (uint32)f16bits(a) | ((uint32)f16bits(b) << 16);
#endif
}

// Reference swizzle: swA(o) = o ^ ((((o>>11)&7) ^ ((o>>7)&1)) << 4).
// Folded forms (all linear fields bit-disjoint -> add == xor), verified in R12:
//  B write: wbase = (q*2048+lc*32+lg*8) ^ ((q&7)<<4) ^ ((lc&4)<<2); + ct*512 carry-free
//  C read : p[ks&3] = (col*2048+kg*16) ^ ((col&7)<<4) ^ {0,64,144,208}[ks&3];
//           addr = p[ks&3] + (ks>>2)*256 (+32768 for A-tile 1), carry-free

// ---- merged pack: blocks [0,3125): xph; blocks [3125,3189): wb ----
__global__ __launch_bounds__(256)
void pack_all(const float* __restrict__ x, u16* __restrict__ xph,
              const float* __restrict__ w, u16* __restrict__ wb) {
    const int bid = blockIdx.x;
    if (bid < 3125) {
        const int tid = bid * 256 + threadIdx.x;   // 800000 = 50000*16
        const int row = tid >> 4;
        const int lp  = tid & 15;
        const float v0 = x[row*CIN +  0 + lp];
        const float v1 = x[row*CIN + 16 + lp];
        const float v2 = x[row*CIN + 32 + lp];
        const float v3 = x[row*CIN + 48 + lp];
        uint2 d;
        d.x = pk2(v0, v1);
        d.y = pk2(v2, v3);
        *(uint2*)&xph[row*CIN + lp*4] = d;
    } else {
        const int u  = (bid - 3125) * 4 + (threadIdx.x >> 6);  // 0..255 (nt,ks) units
        const int nt = u >> 5;            // 0..7
        const int ks = u & 31;            // 0..31
        const int l  = threadIdx.x & 63;
        u16 frag[8];
        #pragma unroll
        for (int e = 0; e < 8; ++e) {
            const int Kp = ks*32 + (l >> 4)*8 + e;
            const int c  = Kp >> 4;
            const int k  = Kp & 15;
            const float val = (k < NK) ? w[(k*CIN + c)*COUT + nt*16 + (l & 15)] : 0.0f;
            frag[e] = f16bits(val);
        }
        *(f16x8*)&wb[((nt*32 + ks)*64 + l)*8] = *(f16x8*)frag;
    }
}

// ---- fused KPConv: QT=32, 8 waves; Phase C: wave = (A-tile, nt-pair) -> 1 LDS A-read feeds 2 MFMA ----
__global__ __launch_bounds__(512, 4)
void kpconv_fused(const float* __restrict__ q_pts,
                  const float* __restrict__ s_pts,
                  const u16*  __restrict__ xph,
                  const u16*  __restrict__ wb,
                  const float* __restrict__ kp,
                  const int*   __restrict__ nind,
                  float* __restrict__ out)
{
    __shared__ u16   fpkAT[QT*1024];   // 65536 B: [q][c][k16] fp16, swizzled
    __shared__ float nb[QT*100];       // 12800 B: centered neighbor coords
    __shared__ u16   inds[QT*NH];      // 2048 B
                                       // total 80384 B -> 2 blocks/CU

    const int t  = threadIdx.x;
    const int q0 = blockIdx.x * QT;

    // ---------------- stage: centered neighbor coords + clamped indices ----------------
    #pragma unroll
    for (int p = t; p < QT*NH; p += 512) {
        const int q = p >> 5, j = p & 31;
        const int qg = q0 + q;
        const int qc = (qg < NQ) ? qg : (NQ - 1);    // clamp for padded tail
        const int ind = nind[qc*NH + j];
        const bool valid = (ind < MS);
        inds[p] = (u16)(valid ? ind : 0);
        float sx, sy, sz;
        if (valid) { sx = s_pts[ind*3+0]; sy = s_pts[ind*3+1]; sz = s_pts[ind*3+2]; }
        else       { sx = 1e6f; sy = 1e6f; sz = 1e6f; }    // shadow -> h = 0
        nb[q*100 + j*3 + 0] = sx - q_pts[qc*3+0];
        nb[q*100 + j*3 + 1] = sy - q_pts[qc*3+1];
        nb[q*100 + j*3 + 2] = sz - q_pts[qc*3+2];
    }
    __syncthreads();

    // ---------------- Phase B (A fused): fpk = h . xg via MFMA ----------------
    // A-frag per lane: row k = lc (15 -> clamped dup, dead via WB zeros), j = lg*8+e.
    {
        const int l  = t & 63, wv = t >> 6;          // wv 0..7
        const int lc = l & 15, lg = l >> 4;
        const int kc = (lc < NK) ? lc : (NK - 1);
        const float kx = kp[kc*3+0], ky = kp[kc*3+1], kz = kp[kc*3+2];
        const uint32 lcxor = (uint32)(lc & 4) << 2;   // folded bit7 term of write swizzle

        // ---- prefetch ALL 32 gathers (4 qi x 8 j-slots), fully static ----
        uint2 v[4][8];
        #pragma unroll
        for (int qi = 0; qi < 4; ++qi) {
            const int q = wv*4 + qi;
            const uint4 iv = *(const uint4*)&inds[q*NH + lg*8];
            uint32 r[8];
            r[0] = iv.x & 0xffffu; r[1] = iv.x >> 16;
            r[2] = iv.y & 0xffffu; r[3] = iv.y >> 16;
            r[4] = iv.z & 0xffffu; r[5] = iv.z >> 16;
            r[6] = iv.w & 0xffffu; r[7] = iv.w >> 16;
            #pragma unroll
            for (int e = 0; e < 8; ++e)
                v[qi][e] = *(const uint2*)(xph + r[e]*CIN + lc*4);
        }

        #pragma unroll
        for (int qi = 0; qi < 4; ++qi) {
            const int q = wv*4 + qi;
            // ---- h for this lane's A-frag (broadcast nb reads within 16-lane groups) ----
            const float* nbq = &nb[q*100 + lg*24];
            const float4 r0 = *(const float4*)(nbq +  0);
            const float4 r1 = *(const float4*)(nbq +  4);
            const float4 r2 = *(const float4*)(nbq +  8);
            const float4 r3 = *(const float4*)(nbq + 12);
            const float4 r4 = *(const float4*)(nbq + 16);
            const float4 r5 = *(const float4*)(nbq + 20);
            float jx[8], jy[8], jz[8];
            jx[0]=r0.x; jy[0]=r0.y; jz[0]=r0.z;
            jx[1]=r0.w; jy[1]=r1.x; jz[1]=r1.y;
            jx[2]=r1.z; jy[2]=r1.w; jz[2]=r2.x;
            jx[3]=r2.y; jy[3]=r2.z; jz[3]=r2.w;
            jx[4]=r3.x; jy[4]=r3.y; jz[4]=r3.z;
            jx[5]=r3.w; jy[5]=r4.x; jz[5]=r4.y;
            jx[6]=r4.z; jy[6]=r4.w; jz[6]=r5.x;
            jx[7]=r5.y; jy[7]=r5.z; jz[7]=r5.w;
            float hh[8];
            #pragma unroll
            for (int e = 0; e < 8; ++e) {
                const float dx = jx[e] - kx;
                const float dy = jy[e] - ky;
                const float dz = jz[e] - kz;
                float h = 1.0f - SQRTF(dx*dx + dy*dy + dz*dz) * INV_EXT;
                hh[e] = (h > 0.0f) ? h : 0.0f;
            }
            uint32 ab[4];
            ab[0] = pk2(hh[0], hh[1]); ab[1] = pk2(hh[2], hh[3]);
            ab[2] = pk2(hh[4], hh[5]); ab[3] = pk2(hh[6], hh[7]);
            const f16x8 a = __builtin_bit_cast(f16x8, *(uint4*)ab);
            // ---- 4 MFMA over channel tiles ----
            f32x4 acc0 = {0,0,0,0}, acc1 = {0,0,0,0}, acc2 = {0,0,0,0}, acc3 = {0,0,0,0};
            #pragma unroll
            for (int ct = 0; ct < 4; ++ct) {
                const uint32 A0 = (ct & 2) ? v[qi][0].y : v[qi][0].x, B0 = (ct & 2) ? v[qi][1].y : v[qi][1].x;
                const uint32 A1 = (ct & 2) ? v[qi][2].y : v[qi][2].x, B1 = (ct & 2) ? v[qi][3].y : v[qi][3].x;
                const uint32 A2 = (ct & 2) ? v[qi][4].y : v[qi][4].x, B2 = (ct & 2) ? v[qi][5].y : v[qi][5].x;
                const uint32 A3 = (ct & 2) ? v[qi][6].y : v[qi][6].x, B3 = (ct & 2) ? v[qi][7].y : v[qi][7].x;
                uint4 bd;
                if (ct & 1) {
                    bd.x = permhi(A0, B0); bd.y = permhi(A1, B1);
                    bd.z = permhi(A2, B2); bd.w = permhi(A3, B3);
                } else {
                    bd.x = permlo(A0, B0); bd.y = permlo(A1, B1);
                    bd.z = permlo(A2, B2); bd.w = permlo(A3, B3);
                }
                const f16x8 b = __builtin_bit_cast(f16x8, bd);
                if      (ct == 0) acc0 = __builtin_amdgcn_mfma_f32_16x16x32_f16(a, b, acc0, 0,0,0);
                else if (ct == 1) acc1 = __builtin_amdgcn_mfma_f32_16x16x32_f16(a, b, acc1, 0,0,0);
                else if (ct == 2) acc2 = __builtin_amdgcn_mfma_f32_16x16x32_f16(a, b, acc2, 0,0,0);
                else              acc3 = __builtin_amdgcn_mfma_f32_16x16x32_f16(a, b, acc3, 0,0,0);
            }
            // ---- writeback, folded swizzle: one addr reg + ds_write imm per ct ----
            {
                const uint32 wbase = ((uint32)(q*2048 + lc*32 + lg*8))
                                     ^ (((uint32)(q & 7)) << 4) ^ lcxor;
                char* wp = (char*)fpkAT + wbase;
                #pragma unroll
                for (int ct = 0; ct < 4; ++ct) {
                    const f32x4 av = (ct==0)?acc0:(ct==1)?acc1:(ct==2)?acc2:acc3;
                    uint2 dv;
                    dv.x = pk2(av[0], av[1]);
                    dv.y = pk2(av[2], av[3]);
                    *(uint2*)(wp + ct*512) = dv;   // ds_write_b64 offset:ct*512
                }
            }
        }
    }

    // ---- Phase C B-frag prefetch (independent of fpkAT; barrier drain lands them free) ----
    const int l   = t & 63;
    const int wv  = t >> 6;
    const int at  = wv >> 2;          // A-tile 0/1 (query half)
    const int ntp = wv & 3;           // n-tile pair: nt0=2*ntp, nt1=2*ntp+1
    const u16* bp0 = wb + ((2*ntp  )*32)*512 + l*8;
    const u16* bp1 = bp0 + 32*512;
    uint4 pb00 = *(const uint4*)(bp0 + 0*512);
    uint4 pb01 = *(const uint4*)(bp0 + 1*512);
    uint4 pb10 = *(const uint4*)(bp1 + 0*512);
    uint4 pb11 = *(const uint4*)(bp1 + 1*512);

    __syncthreads();

    // ---------------- Phase C: out[32 x 128] = fpkAT . WB via MFMA (K=1024) ----------------
    // wave = (at, ntp): per ks ONE LDS A-read feeds TWO MFMAs (nt0, nt1).
    {
        const int col = l & 15;      // A row = query (within A-tile)
        const int kg  = l >> 4;
        f32x4 acc0 = {0.f,0.f,0.f,0.f};   // nt0
        f32x4 acc1 = {0.f,0.f,0.f,0.f};   // nt1
        // folded swizzle: 4 base pointers (ks&3), remaining (ks>>2)*256 carry-free imm
        const uint32 b0 = ((uint32)(col*2048 + kg*16)) ^ (((uint32)(col & 7)) << 4);
        const char* base = (const char*)fpkAT + at*32768;
        const char* p0 = base + (b0);
        const char* p1 = base + (b0 ^ 64u);
        const char* p2 = base + (b0 ^ 144u);   // ^128 (linear bit7) ^16 (swizzle term)
        const char* p3 = base + (b0 ^ 208u);   // ^64 ^128 ^16
        #pragma unroll
        for (int ks = 0; ks < 32; ++ks) {
            const char* sel = ((ks & 3) == 0) ? p0 : ((ks & 3) == 1) ? p1
                            : ((ks & 3) == 2) ? p2 : p3;
            const f16x8 a = *(const f16x8*)(sel + (ks >> 2) * 256);
            uint4 bd0, bd1;
            if      (ks == 0) { bd0 = pb00; bd1 = pb10; }
            else if (ks == 1) { bd0 = pb01; bd1 = pb11; }
            else              { bd0 = *(const uint4*)(bp0 + ks*512);
                                bd1 = *(const uint4*)(bp1 + ks*512); }
            acc0 = __builtin_amdgcn_mfma_f32_16x16x32_f16(a, __builtin_bit_cast(f16x8, bd0), acc0, 0, 0, 0);
            acc1 = __builtin_amdgcn_mfma_f32_16x16x32_f16(a, __builtin_bit_cast(f16x8, bd1), acc1, 0, 0, 0);
        }
        const int rbase = kg * 4;    // D: row=(lane>>4)*4+reg (query), col=lane&15 (channel)
        #pragma unroll
        for (int r = 0; r < 4; ++r) {
            const int row = q0 + at*16 + rbase + r;
            if (row < NQ) {
                out[row*COUT + (2*ntp  )*16 + col] = acc0[r];
                out[row*COUT + (2*ntp+1)*16 + col] = acc1[r];
            }
        }
    }
}

extern "C" void kernel_launch(void* const* d_in, const int* in_sizes, int n_in,
                              void* d_out, int out_size, void* d_ws, size_t ws_size,
                              hipStream_t stream) {
    const float* q_pts = (const float*)d_in[0];
    const float* s_pts = (const float*)d_in[1];
    const float* x     = (const float*)d_in[2];
    const float* wts   = (const float*)d_in[3];
    const float* kp    = (const float*)d_in[4];
    const int*   nind  = (const int*)d_in[5];
    float* out = (float*)d_out;

    u16* wbp = (u16*)d_ws;
    u16* xph = (u16*)((char*)d_ws + WB_BYTES);

    hipLaunchKernelGGL(pack_all, dim3(3125 + 64), dim3(256), 0, stream, x, xph, wts, wbp);
    hipLaunchKernelGGL(kpconv_fused, dim3((NQ + QT - 1) / QT), dim3(512), 0, stream,
                       q_pts, s_pts, xph, wbp, kp, nind, out);
}

// Round 14
// 60.668 us; speedup vs baseline: 1.1799x; 1.1799x over previous
//
#include <hip/hip_runtime.h>

#define NQ     50000
#define MS     50000
#define NH     32
#define NK     15
#define CIN    64
#define COUT   128
#define QT     32
#define INV_EXT (1.0f/0.06f)

typedef unsigned int   uint32;
typedef unsigned short u16;
typedef _Float16 f16;
typedef _Float16 f16x8 __attribute__((ext_vector_type(8)));
typedef float    f32x4 __attribute__((ext_vector_type(4)));

#define WB_BYTES  (8*32*64*8*2)   // 262144
#define XPH_BYTES (MS*CIN*2)

#if __has_builtin(__builtin_amdgcn_sqrtf)
#define SQRTF __builtin_amdgcn_sqrtf
#else
#define SQRTF sqrtf
#endif

__device__ __forceinline__ uint32 permlo(uint32 A, uint32 B) {
#if __has_builtin(__builtin_amdgcn_perm)
    return __builtin_amdgcn_perm(A, B, 0x01000504u);
#else
    return (A & 0xffffu) | (B << 16);
#endif
}
__device__ __forceinline__ uint32 permhi(uint32 A, uint32 B) {
#if __has_builtin(__builtin_amdgcn_perm)
    return __builtin_amdgcn_perm(A, B, 0x03020706u);
#else
    return (A >> 16) | (B & 0xffff0000u);
#endif
}

__device__ __forceinline__ u16 f16bits(float f) {
    return __builtin_bit_cast(u16, (f16)f);
}

__device__ __forceinline__ uint32 pk2(float a, float b) {
#if __has_builtin(__builtin_amdgcn_cvt_pkrtz)
    return __builtin_bit_cast(uint32, __builtin_amdgcn_cvt_pkrtz(a, b));
#else
    return (uint32)f16bits(a) | ((uint32)f16bits(b) << 16);
#endif
}

// Reference swizzle: swA(o) = o ^ ((((o>>11)&7) ^ ((o>>7)&1)) << 4).
// Folded forms (verified R12):
//  B write: wbase = (q*2048+lc*32+lg*8) ^ ((q&7)<<4) ^ ((lc&4)<<2); +ct*512 carry-free
//  C read : p[ks&3] = (col*2048+kg*16) ^ ((col&7)<<4) ^ {0,64,144,208}[ks&3];
//           addr = p[ks&3] + (ks>>2)*256 (+32768 for A-tile 1), carry-free

// ---- merged pack ----
__global__ __launch_bounds__(256)
void pack_all(const float* __restrict__ x, u16* __restrict__ xph,
              const float* __restrict__ w, u16* __restrict__ wb) {
    const int bid = blockIdx.x;
    if (bid < 3125) {
        const int tid = bid * 256 + threadIdx.x;
        const int row = tid >> 4;
        const int lp  = tid & 15;
        const float v0 = x[row*CIN +  0 + lp];
        const float v1 = x[row*CIN + 16 + lp];
        const float v2 = x[row*CIN + 32 + lp];
        const float v3 = x[row*CIN + 48 + lp];
        uint2 d;
        d.x = pk2(v0, v1);
        d.y = pk2(v2, v3);
        *(uint2*)&xph[row*CIN + lp*4] = d;
    } else {
        const int u  = (bid - 3125) * 4 + (threadIdx.x >> 6);
        const int nt = u >> 5;
        const int ks = u & 31;
        const int l  = threadIdx.x & 63;
        u16 frag[8];
        #pragma unroll
        for (int e = 0; e < 8; ++e) {
            const int Kp = ks*32 + (l >> 4)*8 + e;
            const int c  = Kp >> 4;
            const int k  = Kp & 15;
            const float val = (k < NK) ? w[(k*CIN + c)*COUT + nt*16 + (l & 15)] : 0.0f;
            frag[e] = f16bits(val);
        }
        *(f16x8*)&wb[((nt*32 + ks)*64 + l)*8] = *(f16x8*)frag;
    }
}

// ---- fused KPConv: R12 mapping + pinned prefetch + double-buffered Phase C B-loads ----
__global__ __launch_bounds__(512, 4)
void kpconv_fused(const float* __restrict__ q_pts,
                  const float* __restrict__ s_pts,
                  const u16*  __restrict__ xph,
                  const u16*  __restrict__ wb,
                  const float* __restrict__ kp,
                  const int*   __restrict__ nind,
                  float* __restrict__ out)
{
    __shared__ u16   fpkAT[QT*1024];   // 65536 B
    __shared__ float nb[QT*100];       // 12800 B
    __shared__ u16   inds[QT*NH];      // 2048 B -> total 80384 B, 2 blocks/CU

    const int t  = threadIdx.x;
    const int q0 = blockIdx.x * QT;

    // ---------------- stage ----------------
    #pragma unroll
    for (int p = t; p < QT*NH; p += 512) {
        const int q = p >> 5, j = p & 31;
        const int qg = q0 + q;
        const int qc = (qg < NQ) ? qg : (NQ - 1);
        const int ind = nind[qc*NH + j];
        const bool valid = (ind < MS);
        inds[p] = (u16)(valid ? ind : 0);
        float sx, sy, sz;
        if (valid) { sx = s_pts[ind*3+0]; sy = s_pts[ind*3+1]; sz = s_pts[ind*3+2]; }
        else       { sx = 1e6f; sy = 1e6f; sz = 1e6f; }
        nb[q*100 + j*3 + 0] = sx - q_pts[qc*3+0];
        nb[q*100 + j*3 + 1] = sy - q_pts[qc*3+1];
        nb[q*100 + j*3 + 2] = sz - q_pts[qc*3+2];
    }
    __syncthreads();

    // ---------------- Phase B ----------------
    {
        const int l  = t & 63, wv = t >> 6;
        const int lc = l & 15, lg = l >> 4;
        const int kc = (lc < NK) ? lc : (NK - 1);
        const float kx = kp[kc*3+0], ky = kp[kc*3+1], kz = kp[kc*3+2];
        const uint32 lcxor = (uint32)(lc & 4) << 2;

        // prefetch ALL 32 gathers, then pin them before the compute
        uint2 v[4][8];
        #pragma unroll
        for (int qi = 0; qi < 4; ++qi) {
            const int q = wv*4 + qi;
            const uint4 iv = *(const uint4*)&inds[q*NH + lg*8];
            uint32 r[8];
            r[0] = iv.x & 0xffffu; r[1] = iv.x >> 16;
            r[2] = iv.y & 0xffffu; r[3] = iv.y >> 16;
            r[4] = iv.z & 0xffffu; r[5] = iv.z >> 16;
            r[6] = iv.w & 0xffffu; r[7] = iv.w >> 16;
            #pragma unroll
            for (int e = 0; e < 8; ++e)
                v[qi][e] = *(const uint2*)(xph + r[e]*CIN + lc*4);
        }
        __builtin_amdgcn_sched_barrier(0);   // keep gathers issued here (don't sink)

        #pragma unroll
        for (int qi = 0; qi < 4; ++qi) {
            const int q = wv*4 + qi;
            const float* nbq = &nb[q*100 + lg*24];
            const float4 r0 = *(const float4*)(nbq +  0);
            const float4 r1 = *(const float4*)(nbq +  4);
            const float4 r2 = *(const float4*)(nbq +  8);
            const float4 r3 = *(const float4*)(nbq + 12);
            const float4 r4 = *(const float4*)(nbq + 16);
            const float4 r5 = *(const float4*)(nbq + 20);
            float jx[8], jy[8], jz[8];
            jx[0]=r0.x; jy[0]=r0.y; jz[0]=r0.z;
            jx[1]=r0.w; jy[1]=r1.x; jz[1]=r1.y;
            jx[2]=r1.z; jy[2]=r1.w; jz[2]=r2.x;
            jx[3]=r2.y; jy[3]=r2.z; jz[3]=r2.w;
            jx[4]=r3.x; jy[4]=r3.y; jz[4]=r3.z;
            jx[5]=r3.w; jy[5]=r4.x; jz[5]=r4.y;
            jx[6]=r4.z; jy[6]=r4.w; jz[6]=r5.x;
            jx[7]=r5.y; jy[7]=r5.z; jz[7]=r5.w;
            float hh[8];
            #pragma unroll
            for (int e = 0; e < 8; ++e) {
                const float dx = jx[e] - kx;
                const float dy = jy[e] - ky;
                const float dz = jz[e] - kz;
                float h = 1.0f - SQRTF(dx*dx + dy*dy + dz*dz) * INV_EXT;
                hh[e] = (h > 0.0f) ? h : 0.0f;
            }
            uint32 ab[4];
            ab[0] = pk2(hh[0], hh[1]); ab[1] = pk2(hh[2], hh[3]);
            ab[2] = pk2(hh[4], hh[5]); ab[3] = pk2(hh[6], hh[7]);
            const f16x8 a = __builtin_bit_cast(f16x8, *(uint4*)ab);
            f32x4 acc0 = {0,0,0,0}, acc1 = {0,0,0,0}, acc2 = {0,0,0,0}, acc3 = {0,0,0,0};
            #pragma unroll
            for (int ct = 0; ct < 4; ++ct) {
                const uint32 A0 = (ct & 2) ? v[qi][0].y : v[qi][0].x, B0 = (ct & 2) ? v[qi][1].y : v[qi][1].x;
                const uint32 A1 = (ct & 2) ? v[qi][2].y : v[qi][2].x, B1 = (ct & 2) ? v[qi][3].y : v[qi][3].x;
                const uint32 A2 = (ct & 2) ? v[qi][4].y : v[qi][4].x, B2 = (ct & 2) ? v[qi][5].y : v[qi][5].x;
                const uint32 A3 = (ct & 2) ? v[qi][6].y : v[qi][6].x, B3 = (ct & 2) ? v[qi][7].y : v[qi][7].x;
                uint4 bd;
                if (ct & 1) {
                    bd.x = permhi(A0, B0); bd.y = permhi(A1, B1);
                    bd.z = permhi(A2, B2); bd.w = permhi(A3, B3);
                } else {
                    bd.x = permlo(A0, B0); bd.y = permlo(A1, B1);
                    bd.z = permlo(A2, B2); bd.w = permlo(A3, B3);
                }
                const f16x8 b = __builtin_bit_cast(f16x8, bd);
                if      (ct == 0) acc0 = __builtin_amdgcn_mfma_f32_16x16x32_f16(a, b, acc0, 0,0,0);
                else if (ct == 1) acc1 = __builtin_amdgcn_mfma_f32_16x16x32_f16(a, b, acc1, 0,0,0);
                else if (ct == 2) acc2 = __builtin_amdgcn_mfma_f32_16x16x32_f16(a, b, acc2, 0,0,0);
                else              acc3 = __builtin_amdgcn_mfma_f32_16x16x32_f16(a, b, acc3, 0,0,0);
            }
            {
                const uint32 wbase = ((uint32)(q*2048 + lc*32 + lg*8))
                                     ^ (((uint32)(q & 7)) << 4) ^ lcxor;
                char* wp = (char*)fpkAT + wbase;
                #pragma unroll
                for (int ct = 0; ct < 4; ++ct) {
                    const f32x4 av = (ct==0)?acc0:(ct==1)?acc1:(ct==2)?acc2:acc3;
                    uint2 dv;
                    dv.x = pk2(av[0], av[1]);
                    dv.y = pk2(av[2], av[3]);
                    *(uint2*)(wp + ct*512) = dv;
                }
            }
        }
    }

    // ---- Phase C group-0 B-prefetch (independent of fpkAT; in flight across barrier) ----
    const int l  = t & 63;
    const int nt = t >> 6;              // R12 mapping: wave = nt, covers BOTH A-tiles
    const u16* bp = wb + (nt*32)*512 + l*8;
    uint4 bufA[8], bufB[8];
    #pragma unroll
    for (int e = 0; e < 8; ++e) bufA[e] = *(const uint4*)(bp + e*512);

    __syncthreads();

    // ---------------- Phase C: out[32 x 128], double-buffered B stream ----------------
    {
        const int col = l & 15;
        const int kg  = l >> 4;
        f32x4 acc0 = {0.f,0.f,0.f,0.f};   // queries q0..q0+15
        f32x4 acc1 = {0.f,0.f,0.f,0.f};   // queries q0+16..q0+31
        const uint32 b0 = ((uint32)(col*2048 + kg*16)) ^ (((uint32)(col & 7)) << 4);
        const char* base = (const char*)fpkAT;
        const char* p0 = base + (b0);
        const char* p1 = base + (b0 ^ 64u);
        const char* p2 = base + (b0 ^ 144u);
        const char* p3 = base + (b0 ^ 208u);

#define PROC(G, BUF)                                                              \
        _Pragma("unroll")                                                         \
        for (int e = 0; e < 8; ++e) {                                             \
            const int ks = (G)*8 + e;                                             \
            const char* sel = ((ks & 3) == 0) ? p0 : ((ks & 3) == 1) ? p1         \
                            : ((ks & 3) == 2) ? p2 : p3;                          \
            const int off = (ks >> 2) * 256;                                      \
            const f16x8 a0 = *(const f16x8*)(sel + off);                          \
            const f16x8 a1 = *(const f16x8*)(sel + off + 32768);                  \
            const f16x8 b  = __builtin_bit_cast(f16x8, BUF[e]);                   \
            acc0 = __builtin_amdgcn_mfma_f32_16x16x32_f16(a0, b, acc0, 0, 0, 0);  \
            acc1 = __builtin_amdgcn_mfma_f32_16x16x32_f16(a1, b, acc1, 0, 0, 0);  \
        }

        // load group 1 while processing group 0, etc.
        #pragma unroll
        for (int e = 0; e < 8; ++e) bufB[e] = *(const uint4*)(bp + (8 + e)*512);
        __builtin_amdgcn_sched_barrier(0);
        PROC(0, bufA)
        #pragma unroll
        for (int e = 0; e < 8; ++e) bufA[e] = *(const uint4*)(bp + (16 + e)*512);
        __builtin_amdgcn_sched_barrier(0);
        PROC(1, bufB)
        #pragma unroll
        for (int e = 0; e < 8; ++e) bufB[e] = *(const uint4*)(bp + (24 + e)*512);
        __builtin_amdgcn_sched_barrier(0);
        PROC(2, bufA)
        PROC(3, bufB)
#undef PROC

        const int rbase = kg * 4;
        #pragma unroll
        for (int r = 0; r < 4; ++r) {
            const int row0 = q0 + rbase + r;
            const int row1 = row0 + 16;
            if (row0 < NQ) out[row0*COUT + nt*16 + col] = acc0[r];
            if (row1 < NQ) out[row1*COUT + nt*16 + col] = acc1[r];
        }
    }
}

extern "C" void kernel_launch(void* const* d_in, const int* in_sizes, int n_in,
                              void* d_out, int out_size, void* d_ws, size_t ws_size,
                              hipStream_t stream) {
    const float* q_pts = (const float*)d_in[0];
    const float* s_pts = (const float*)d_in[1];
    const float* x     = (const float*)d_in[2];
    const float* wts   = (const float*)d_in[3];
    const float* kp    = (const float*)d_in[4];
    const int*   nind  = (const int*)d_in[5];
    float* out = (float*)d_out;

    u16* wbp = (u16*)d_ws;
    u16* xph = (u16*)((char*)d_ws + WB_BYTES);

    hipLaunchKernelGGL(pack_all, dim3(3125 + 64), dim3(256), 0, stream, x, xph, wts, wbp);
    hipLaunchKernelGGL(kpconv_fused, dim3((NQ + QT - 1) / QT), dim3(512), 0, stream,
                       q_pts, s_pts, xph, wbp, kp, nind, out);
}

// Round 15
// 60.646 us; speedup vs baseline: 1.1803x; 1.0004x over previous
//
#include <hip/hip_runtime.h>

#define NQ     50000
#define MS     50000
#define NH     32
#define NK     15
#define CIN    64
#define COUT   128
#define QT     32
#define INV_EXT (1.0f/0.06f)

typedef unsigned int   uint32;
typedef unsigned short u16;
typedef _Float16 f16;
typedef _Float16 f16x8 __attribute__((ext_vector_type(8)));
typedef float    f32x4 __attribute__((ext_vector_type(4)));

#define WB_BYTES  (8*32*64*8*2)   // 262144
#define XPH_BYTES (MS*CIN*2)

#if __has_builtin(__builtin_amdgcn_sqrtf)
#define SQRTF __builtin_amdgcn_sqrtf
#else
#define SQRTF sqrtf
#endif

__device__ __forceinline__ uint32 permlo(uint32 A, uint32 B) {
#if __has_builtin(__builtin_amdgcn_perm)
    return __builtin_amdgcn_perm(A, B, 0x01000504u);
#else
    return (A & 0xffffu) | (B << 16);
#endif
}
__device__ __forceinline__ uint32 permhi(uint32 A, uint32 B) {
#if __has_builtin(__builtin_amdgcn_perm)
    return __builtin_amdgcn_perm(A, B, 0x03020706u);
#else
    return (A >> 16) | (B & 0xffff0000u);
#endif
}

__device__ __forceinline__ u16 f16bits(float f) {
    return __builtin_bit_cast(u16, (f16)f);
}

__device__ __forceinline__ uint32 pk2(float a, float b) {
#if __has_builtin(__builtin_amdgcn_cvt_pkrtz)
    return __builtin_bit_cast(uint32, __builtin_amdgcn_cvt_pkrtz(a, b));
#else
    return (uint32)f16bits(a) | ((uint32)f16bits(b) << 16);
#endif
}

// pinned (un-sinkable) global loads
__device__ __forceinline__ uint2 ld_b64(const void* p) {
    uint2 r;
    asm volatile("global_load_dwordx2 %0, %1, off" : "=v"(r) : "v"(p));
    return r;
}
__device__ __forceinline__ uint4 ld_b128(const void* p) {
    uint4 r;
    asm volatile("global_load_dwordx4 %0, %1, off" : "=v"(r) : "v"(p));
    return r;
}
#define WAIT_VM(n) do { asm volatile("s_waitcnt vmcnt(" #n ")"); \
                        __builtin_amdgcn_sched_barrier(0); } while (0)

// Reference swizzle: swA(o) = o ^ ((((o>>11)&7) ^ ((o>>7)&1)) << 4).  Folded forms verified R12.

// ---- merged pack ----
__global__ __launch_bounds__(256)
void pack_all(const float* __restrict__ x, u16* __restrict__ xph,
              const float* __restrict__ w, u16* __restrict__ wb) {
    const int bid = blockIdx.x;
    if (bid < 3125) {
        const int tid = bid * 256 + threadIdx.x;
        const int row = tid >> 4;
        const int lp  = tid & 15;
        const float v0 = x[row*CIN +  0 + lp];
        const float v1 = x[row*CIN + 16 + lp];
        const float v2 = x[row*CIN + 32 + lp];
        const float v3 = x[row*CIN + 48 + lp];
        uint2 d;
        d.x = pk2(v0, v1);
        d.y = pk2(v2, v3);
        *(uint2*)&xph[row*CIN + lp*4] = d;
    } else {
        const int u  = (bid - 3125) * 4 + (threadIdx.x >> 6);
        const int nt = u >> 5;
        const int ks = u & 31;
        const int l  = threadIdx.x & 63;
        u16 frag[8];
        #pragma unroll
        for (int e = 0; e < 8; ++e) {
            const int Kp = ks*32 + (l >> 4)*8 + e;
            const int c  = Kp >> 4;
            const int k  = Kp & 15;
            const float val = (k < NK) ? w[(k*CIN + c)*COUT + nt*16 + (l & 15)] : 0.0f;
            frag[e] = f16bits(val);
        }
        *(f16x8*)&wb[((nt*32 + ks)*64 + l)*8] = *(f16x8*)frag;
    }
}

// ---- fused KPConv: asm-pinned gathers (Phase B) + asm dbuf B-stream (Phase C) ----
__global__ __launch_bounds__(512, 4)
void kpconv_fused(const float* __restrict__ q_pts,
                  const float* __restrict__ s_pts,
                  const u16*  __restrict__ xph,
                  const u16*  __restrict__ wb,
                  const float* __restrict__ kp,
                  const int*   __restrict__ nind,
                  float* __restrict__ out)
{
    __shared__ u16   fpkAT[QT*1024];   // 65536 B
    __shared__ float nb[QT*100];       // 12800 B
    __shared__ u16   inds[QT*NH];      // 2048 B -> 80384 B, 2 blocks/CU

    const int t  = threadIdx.x;
    const int q0 = blockIdx.x * QT;

    // ---------------- stage ----------------
    #pragma unroll
    for (int p = t; p < QT*NH; p += 512) {
        const int q = p >> 5, j = p & 31;
        const int qg = q0 + q;
        const int qc = (qg < NQ) ? qg : (NQ - 1);
        const int ind = nind[qc*NH + j];
        const bool valid = (ind < MS);
        inds[p] = (u16)(valid ? ind : 0);
        float sx, sy, sz;
        if (valid) { sx = s_pts[ind*3+0]; sy = s_pts[ind*3+1]; sz = s_pts[ind*3+2]; }
        else       { sx = 1e6f; sy = 1e6f; sz = 1e6f; }
        nb[q*100 + j*3 + 0] = sx - q_pts[qc*3+0];
        nb[q*100 + j*3 + 1] = sy - q_pts[qc*3+1];
        nb[q*100 + j*3 + 2] = sz - q_pts[qc*3+2];
    }
    __syncthreads();

    // ---------------- Phase B ----------------
    {
        const int l  = t & 63, wv = t >> 6;
        const int lc = l & 15, lg = l >> 4;
        const int kc = (lc < NK) ? lc : (NK - 1);
        const float kx = kp[kc*3+0], ky = kp[kc*3+1], kz = kp[kc*3+2];
        const uint32 lcxor = (uint32)(lc & 4) << 2;

        #pragma unroll
        for (int half = 0; half < 2; ++half) {
            const int qA = wv*4 + half*2;
            const int qB = qA + 1;

            // ---- issue 16 pinned gathers (2 queries x 8 j-slots) ----
            uint2 vA[8], vB[8];
            {
                const uint4 iv = *(const uint4*)&inds[qA*NH + lg*8];
                uint32 r[8];
                r[0] = iv.x & 0xffffu; r[1] = iv.x >> 16;
                r[2] = iv.y & 0xffffu; r[3] = iv.y >> 16;
                r[4] = iv.z & 0xffffu; r[5] = iv.z >> 16;
                r[6] = iv.w & 0xffffu; r[7] = iv.w >> 16;
                #pragma unroll
                for (int e = 0; e < 8; ++e) vA[e] = ld_b64(xph + r[e]*CIN + lc*4);
            }
            {
                const uint4 iv = *(const uint4*)&inds[qB*NH + lg*8];
                uint32 r[8];
                r[0] = iv.x & 0xffffu; r[1] = iv.x >> 16;
                r[2] = iv.y & 0xffffu; r[3] = iv.y >> 16;
                r[4] = iv.z & 0xffffu; r[5] = iv.z >> 16;
                r[6] = iv.w & 0xffffu; r[7] = iv.w >> 16;
                #pragma unroll
                for (int e = 0; e < 8; ++e) vB[e] = ld_b64(xph + r[e]*CIN + lc*4);
            }

            // ---- h-compute for both queries (independent of gathers) ----
            f16x8 aF[2];
            #pragma unroll
            for (int s = 0; s < 2; ++s) {
                const int q = qA + s;
                const float* nbq = &nb[q*100 + lg*24];
                const float4 r0 = *(const float4*)(nbq +  0);
                const float4 r1 = *(const float4*)(nbq +  4);
                const float4 r2 = *(const float4*)(nbq +  8);
                const float4 r3 = *(const float4*)(nbq + 12);
                const float4 r4 = *(const float4*)(nbq + 16);
                const float4 r5 = *(const float4*)(nbq + 20);
                float jx[8], jy[8], jz[8];
                jx[0]=r0.x; jy[0]=r0.y; jz[0]=r0.z;
                jx[1]=r0.w; jy[1]=r1.x; jz[1]=r1.y;
                jx[2]=r1.z; jy[2]=r1.w; jz[2]=r2.x;
                jx[3]=r2.y; jy[3]=r2.z; jz[3]=r2.w;
                jx[4]=r3.x; jy[4]=r3.y; jz[4]=r3.z;
                jx[5]=r3.w; jy[5]=r4.x; jz[5]=r4.y;
                jx[6]=r4.z; jy[6]=r4.w; jz[6]=r5.x;
                jx[7]=r5.y; jy[7]=r5.z; jz[7]=r5.w;
                float hh[8];
                #pragma unroll
                for (int e = 0; e < 8; ++e) {
                    const float dx = jx[e] - kx;
                    const float dy = jy[e] - ky;
                    const float dz = jz[e] - kz;
                    float h = 1.0f - SQRTF(dx*dx + dy*dy + dz*dz) * INV_EXT;
                    hh[e] = (h > 0.0f) ? h : 0.0f;
                }
                uint32 ab[4];
                ab[0] = pk2(hh[0], hh[1]); ab[1] = pk2(hh[2], hh[3]);
                ab[2] = pk2(hh[4], hh[5]); ab[3] = pk2(hh[6], hh[7]);
                aF[s] = __builtin_bit_cast(f16x8, *(uint4*)ab);
            }

            WAIT_VM(0);   // gathers landed; values pinned in vA/vB

            // ---- process both queries: perms + 4 MFMA + swizzled ds_write ----
            #pragma unroll
            for (int s = 0; s < 2; ++s) {
                const int q = qA + s;
                const uint2* v = s ? vB : vA;
                const f16x8 a = aF[s];
                f32x4 acc0 = {0,0,0,0}, acc1 = {0,0,0,0}, acc2 = {0,0,0,0}, acc3 = {0,0,0,0};
                #pragma unroll
                for (int ct = 0; ct < 4; ++ct) {
                    const uint32 A0 = (ct & 2) ? v[0].y : v[0].x, B0 = (ct & 2) ? v[1].y : v[1].x;
                    const uint32 A1 = (ct & 2) ? v[2].y : v[2].x, B1 = (ct & 2) ? v[3].y : v[3].x;
                    const uint32 A2 = (ct & 2) ? v[4].y : v[4].x, B2 = (ct & 2) ? v[5].y : v[5].x;
                    const uint32 A3 = (ct & 2) ? v[6].y : v[6].x, B3 = (ct & 2) ? v[7].y : v[7].x;
                    uint4 bd;
                    if (ct & 1) {
                        bd.x = permhi(A0, B0); bd.y = permhi(A1, B1);
                        bd.z = permhi(A2, B2); bd.w = permhi(A3, B3);
                    } else {
                        bd.x = permlo(A0, B0); bd.y = permlo(A1, B1);
                        bd.z = permlo(A2, B2); bd.w = permlo(A3, B3);
                    }
                    const f16x8 b = __builtin_bit_cast(f16x8, bd);
                    if      (ct == 0) acc0 = __builtin_amdgcn_mfma_f32_16x16x32_f16(a, b, acc0, 0,0,0);
                    else if (ct == 1) acc1 = __builtin_amdgcn_mfma_f32_16x16x32_f16(a, b, acc1, 0,0,0);
                    else if (ct == 2) acc2 = __builtin_amdgcn_mfma_f32_16x16x32_f16(a, b, acc2, 0,0,0);
                    else              acc3 = __builtin_amdgcn_mfma_f32_16x16x32_f16(a, b, acc3, 0,0,0);
                }
                const uint32 wbase = ((uint32)(q*2048 + lc*32 + lg*8))
                                     ^ (((uint32)(q & 7)) << 4) ^ lcxor;
                char* wp = (char*)fpkAT + wbase;
                #pragma unroll
                for (int ct = 0; ct < 4; ++ct) {
                    const f32x4 av = (ct==0)?acc0:(ct==1)?acc1:(ct==2)?acc2:acc3;
                    uint2 dv;
                    dv.x = pk2(av[0], av[1]);
                    dv.y = pk2(av[2], av[3]);
                    *(uint2*)(wp + ct*512) = dv;
                }
            }
        }
    }

    const int l  = t & 63;
    const int nt = t >> 6;              // wave = nt, covers BOTH A-tiles (R12 mapping)
    const u16* bp = wb + (nt*32)*512 + l*8;

    __syncthreads();

    // ---------------- Phase C: asm double-buffered B stream, counted vmcnt ----------------
    {
        const int col = l & 15;
        const int kg  = l >> 4;
        f32x4 acc0 = {0.f,0.f,0.f,0.f};
        f32x4 acc1 = {0.f,0.f,0.f,0.f};
        const uint32 b0 = ((uint32)(col*2048 + kg*16)) ^ (((uint32)(col & 7)) << 4);
        const char* base = (const char*)fpkAT;
        const char* p0 = base + (b0);
        const char* p1 = base + (b0 ^ 64u);
        const char* p2 = base + (b0 ^ 144u);
        const char* p3 = base + (b0 ^ 208u);

        uint4 bufA[8], bufB[8];
        #pragma unroll
        for (int e = 0; e < 8; ++e) bufA[e] = ld_b128(bp + e*512);        // g0
        #pragma unroll
        for (int e = 0; e < 8; ++e) bufB[e] = ld_b128(bp + (8+e)*512);    // g1

#define PROC(G, BUF)                                                              \
        _Pragma("unroll")                                                         \
        for (int e = 0; e < 8; ++e) {                                             \
            const int ks = (G)*8 + e;                                             \
            const char* sel = ((ks & 3) == 0) ? p0 : ((ks & 3) == 1) ? p1         \
                            : ((ks & 3) == 2) ? p2 : p3;                          \
            const int off = (ks >> 2) * 256;                                      \
            const f16x8 a0 = *(const f16x8*)(sel + off);                          \
            const f16x8 a1 = *(const f16x8*)(sel + off + 32768);                  \
            const f16x8 b  = __builtin_bit_cast(f16x8, BUF[e]);                   \
            acc0 = __builtin_amdgcn_mfma_f32_16x16x32_f16(a0, b, acc0, 0, 0, 0);  \
            acc1 = __builtin_amdgcn_mfma_f32_16x16x32_f16(a1, b, acc1, 0, 0, 0);  \
        }

        WAIT_VM(8);    // g0 landed (g1 in flight)
        PROC(0, bufA)
        #pragma unroll
        for (int e = 0; e < 8; ++e) bufA[e] = ld_b128(bp + (16+e)*512);   // g2
        WAIT_VM(8);    // g1 landed (g2 in flight)
        PROC(1, bufB)
        #pragma unroll
        for (int e = 0; e < 8; ++e) bufB[e] = ld_b128(bp + (24+e)*512);   // g3
        WAIT_VM(8);    // g2 landed (g3 in flight)
        PROC(2, bufA)
        WAIT_VM(0);    // g3 landed
        PROC(3, bufB)
#undef PROC

        const int rbase = kg * 4;
        #pragma unroll
        for (int r = 0; r < 4; ++r) {
            const int row0 = q0 + rbase + r;
            const int row1 = row0 + 16;
            if (row0 < NQ) out[row0*COUT + nt*16 + col] = acc0[r];
            if (row1 < NQ) out[row1*COUT + nt*16 + col] = acc1[r];
        }
    }
}

extern "C" void kernel_launch(void* const* d_in, const int* in_sizes, int n_in,
                              void* d_out, int out_size, void* d_ws, size_t ws_size,
                              hipStream_t stream) {
    const float* q_pts = (const float*)d_in[0];
    const float* s_pts = (const float*)d_in[1];
    const float* x     = (const float*)d_in[2];
    const float* wts   = (const float*)d_in[3];
    const float* kp    = (const float*)d_in[4];
    const int*   nind  = (const int*)d_in[5];
    float* out = (float*)d_out;

    u16* wbp = (u16*)d_ws;
    u16* xph = (u16*)((char*)d_ws + WB_BYTES);

    hipLaunchKernelGGL(pack_all, dim3(3125 + 64), dim3(256), 0, stream, x, xph, wts, wbp);
    hipLaunchKernelGGL(kpconv_fused, dim3((NQ + QT - 1) / QT), dim3(512), 0, stream,
                       q_pts, s_pts, xph, wbp, kp, nind, out);
}